// Round 1
// baseline (433.901 us; speedup 1.0000x reference)
//
#include <hip/hip_runtime.h>
#include <stdint.h>

typedef unsigned short u16;
typedef __attribute__((ext_vector_type(8))) short short8;
typedef __attribute__((ext_vector_type(4))) float f32x4;

#define PI_F 3.14159265358979323846f
#define L_SEQ 2048
#define NFFT 4096
#define DM 1024
#define TW 3072
#define BATCH 4

__device__ __forceinline__ u16 f2bf(float f){
  union { float f; uint32_t u; } v; v.f = f;
  uint32_t r = v.u + 0x7fffu + ((v.u >> 16) & 1u);
  return (u16)(r >> 16);
}
__device__ __forceinline__ float bf2f(u16 h){
  union { uint32_t u; float f; } v; v.u = ((uint32_t)h) << 16;
  return v.f;
}

__device__ __forceinline__ void async16(const void* g, void* l){
  __builtin_amdgcn_global_load_lds(
      (const __attribute__((address_space(1))) void*)g,
      (__attribute__((address_space(3))) void*)l, 16, 0, 0);
}

// ---------------- convert u (fp32 -> bf16), vectorized ----------------
__global__ void k_convert_u(const float4* __restrict__ in, u16* __restrict__ outp, int n4){
  int idx = blockIdx.x * blockDim.x + threadIdx.x;
  int stride = gridDim.x * blockDim.x;
  for (int i = idx; i < n4; i += stride){
    float4 v = in[i];
    u16 r0 = f2bf(v.x), r1 = f2bf(v.y), r2 = f2bf(v.z), r3 = f2bf(v.w);
    u16* o = outp + (size_t)i * 4;
    o[0] = r0; o[1] = r1; o[2] = r2; o[3] = r3;
  }
}

// ---------------- transpose weight fp32 (K,N) -> bf16 (N,K) ----------------
__global__ void k_transpose_w(const float* __restrict__ in, u16* __restrict__ outp, int K, int N){
  __shared__ float tile[32][33];
  int n0 = blockIdx.x * 32, k0 = blockIdx.y * 32;
  int x = threadIdx.x, y = threadIdx.y;
  for (int i = 0; i < 4; ++i)
    tile[y + i*8][x] = in[(size_t)(k0 + y + i*8) * N + n0 + x];
  __syncthreads();
  for (int i = 0; i < 4; ++i)
    outp[(size_t)(n0 + y + i*8) * K + k0 + x] = f2bf(tile[x][y + i*8]);
}

// ---------------- filter MLP: H2 (2048 x 64) ----------------
__global__ void k_filter_h2(const float* __restrict__ w0, const float* __restrict__ b0, const float* __restrict__ f0,
                            const float* __restrict__ w1, const float* __restrict__ b1, const float* __restrict__ f1,
                            const float* __restrict__ w2, const float* __restrict__ b2, const float* __restrict__ f2,
                            float* __restrict__ H2){
  int t = blockIdx.x;
  int j = threadIdx.x; // 0..63
  float tn = t * (1.0f / 2047.0f);
  float ph = 1e-4f * 2.0f * PI_F * (float)t * (1.0f / 2048.0f);
  float z0 = tn, z1 = cosf(ph), z2 = -sinf(ph);
  __shared__ float hs[64];
  float pre = z0 * w0[j] + z1 * w0[64 + j] + z2 * w0[128 + j] + b0[j];
  float h = sinf(f0[j] * pre);
  hs[j] = h;
  __syncthreads();
  float acc = b1[j];
  for (int i = 0; i < 64; ++i) acc += hs[i] * w1[i*64 + j];
  h = sinf(f1[j] * acc);
  __syncthreads();
  hs[j] = h;
  __syncthreads();
  acc = b2[j];
  for (int i = 0; i < 64; ++i) acc += hs[i] * w2[i*64 + j];
  h = sinf(f2[j] * acc);
  H2[t*64 + j] = h;
}

// ---------------- FFT helpers (n=4096, 256 threads) ----------------
// DIF forward: natural in -> bit-reversed out.
__device__ __forceinline__ void fft_dif(float2* a, int tid){
  for (int p = 12; p >= 1; --p){
    int half = 1 << (p - 1);
    float wstep = -PI_F / (float)half;
    for (int i = 0; i < 8; ++i){
      int bfi = tid + (i << 8);
      int blk = bfi >> (p - 1);
      int j = bfi & (half - 1);
      int i0 = (blk << p) + j;
      int i1 = i0 + half;
      float2 u = a[i0], v = a[i1];
      float ang = wstep * (float)j;
      float sn, cs; __sincosf(ang, &sn, &cs);
      float dx = u.x - v.x, dy = u.y - v.y;
      a[i0] = make_float2(u.x + v.x, u.y + v.y);
      a[i1] = make_float2(dx*cs - dy*sn, dx*sn + dy*cs);
    }
    __syncthreads();
  }
}
// DIT inverse (unscaled): bit-reversed in -> natural out.
__device__ __forceinline__ void fft_dit_inv(float2* a, int tid){
  for (int p = 1; p <= 12; ++p){
    int half = 1 << (p - 1);
    float wstep = PI_F / (float)half;
    for (int i = 0; i < 8; ++i){
      int bfi = tid + (i << 8);
      int blk = bfi >> (p - 1);
      int j = bfi & (half - 1);
      int i0 = (blk << p) + j;
      int i1 = i0 + half;
      float2 u = a[i0], v = a[i1];
      float ang = wstep * (float)j;
      float sn, cs; __sincosf(ang, &sn, &cs);
      float tx = v.x*cs - v.y*sn, ty = v.x*sn + v.y*cs;
      a[i0] = make_float2(u.x + tx, u.y + ty);
      a[i1] = make_float2(u.x - tx, u.y - ty);
    }
    __syncthreads();
  }
}

// ---------------- per-channel filter spectrum: K_f[c] = DFT(k_c)/n, bit-rev order ----------------
__global__ void k_filter_fft(const float* __restrict__ H2, const float* __restrict__ w3,
                             float2* __restrict__ Kf){
  int c = blockIdx.x;
  int tid = threadIdx.x;
  __shared__ float2 a[NFFT];
  __shared__ float wcol[64];
  if (tid < 64) wcol[tid] = w3[tid * DM + c];
  __syncthreads();
  float absd = 3.070113457325394f + 12.280453829301576f * ((float)c * (1.0f / 1023.0f));
  for (int i = 0; i < 8; ++i){
    int t = tid + (i << 8);
    const float* hr = &H2[t * 64];
    float s = 0.f;
    #pragma unroll 8
    for (int j = 0; j < 64; ++j) s += hr[j] * wcol[j];
    float mod = __expf(-((float)t * (1.0f / 2047.0f)) * absd);
    a[t] = make_float2(s * mod, 0.f);
    a[t + L_SEQ] = make_float2(0.f, 0.f);
  }
  __syncthreads();
  fft_dif(a, tid);
  const float inv = 1.0f / (float)NFFT;
  for (int i = 0; i < 16; ++i){
    int idx = tid + (i << 8);
    float2 v = a[idx];
    Kf[(size_t)c * NFFT + idx] = make_float2(v.x * inv, v.y * inv);
  }
}

// ---------------- GEMM: C(M,N) = A(M,K)bf16 * Bt(N,K)bf16^T + bias ----------------
template<bool OUT_BF16>
__global__ __launch_bounds__(256) void k_gemm(const u16* __restrict__ A, const u16* __restrict__ Bt,
                                              const float* __restrict__ bias, void* __restrict__ Cout,
                                              int M, int N, int K){
  __shared__ __align__(16) u16 As[128 * 32];
  __shared__ __align__(16) u16 Bs[128 * 32];
  int m0 = blockIdx.y * 128;
  int n0 = blockIdx.x * 128;
  int tid = threadIdx.x;
  int wave = tid >> 6, lane = tid & 63;
  int wm = wave >> 1, wn = wave & 1;
  f32x4 acc[4][4] = {};
  int lrow = lane & 15;
  int lk = (lane >> 4) * 8;
  int ksteps = K >> 5;
  for (int kt = 0; kt < ksteps; ++kt){
    int k0 = kt << 5;
    // stage A and B tiles: each wave 2 chunks of 16 rows each
    #pragma unroll
    for (int half = 0; half < 2; ++half){
      int row = wave * 32 + half * 16 + (lane >> 2);
      int chunk = (lane & 3) * 8;
      async16(A + (size_t)(m0 + row) * K + k0 + chunk, &As[(wave*32 + half*16) * 32]);
      async16(Bt + (size_t)(n0 + row) * K + k0 + chunk, &Bs[(wave*32 + half*16) * 32]);
    }
    __syncthreads();
    short8 af[4], bfr[4];
    #pragma unroll
    for (int i = 0; i < 4; ++i){
      af[i]  = *(const short8*)&As[(wm*64 + i*16 + lrow) * 32 + lk];
      bfr[i] = *(const short8*)&Bs[(wn*64 + i*16 + lrow) * 32 + lk];
    }
    #pragma unroll
    for (int i = 0; i < 4; ++i)
      #pragma unroll
      for (int j = 0; j < 4; ++j)
        acc[i][j] = __builtin_amdgcn_mfma_f32_16x16x32_bf16(af[i], bfr[j], acc[i][j], 0, 0, 0);
    __syncthreads();
  }
  // epilogue: C/D layout col = lane&15, row = (lane>>4)*4 + r
  #pragma unroll
  for (int j = 0; j < 4; ++j){
    int col = n0 + wn*64 + j*16 + (lane & 15);
    float bv = bias[col];
    #pragma unroll
    for (int i = 0; i < 4; ++i){
      int rbase = m0 + wm*64 + i*16 + (lane >> 4) * 4;
      #pragma unroll
      for (int r = 0; r < 4; ++r){
        float val = acc[i][j][r] + bv;
        if (OUT_BF16) ((u16*)Cout)[(size_t)(rbase + r) * N + col] = f2bf(val);
        else ((float*)Cout)[(size_t)(rbase + r) * N + col] = val;
      }
    }
  }
}

// ---------------- short conv + gate + transpose to (b,d,l) ----------------
__global__ void k_shortconv(const u16* __restrict__ up, const float* __restrict__ sw,
                            const float* __restrict__ sb,
                            u16* __restrict__ gOut, u16* __restrict__ x0Out){
  __shared__ float s[3][32][130];
  int t0 = blockIdx.x * 128;
  int c0 = blockIdx.y * 32;
  int b  = blockIdx.z;
  int tid = threadIdx.x;
  int cc = tid & 31, rr = tid >> 5;
  for (int g2 = 0; g2 < 3; ++g2){
    for (int r = rr; r < 130; r += 8){
      int t = t0 + r - 2;
      float v = 0.f;
      if (t >= 0) v = bf2f(up[((size_t)(b * L_SEQ + t)) * TW + g2 * DM + c0 + cc]);
      s[g2][cc][r] = v;
    }
  }
  __syncthreads();
  int cglob = c0 + cc;
  float w00 = sw[cglob*3+0],        w01 = sw[cglob*3+1],        w02 = sw[cglob*3+2];
  float w10 = sw[(DM+cglob)*3+0],   w11 = sw[(DM+cglob)*3+1],   w12 = sw[(DM+cglob)*3+2];
  float w20 = sw[(2*DM+cglob)*3+0], w21 = sw[(2*DM+cglob)*3+1], w22 = sw[(2*DM+cglob)*3+2];
  float sb0 = sb[cglob], sb1 = sb[DM+cglob], sb2 = sb[2*DM+cglob];
  size_t ob = ((size_t)(b * DM + cglob)) * L_SEQ + t0;
  for (int q = 0; q < 16; ++q){
    int tt = rr * 16 + q;
    float x0v = w00*s[0][cc][tt] + w01*s[0][cc][tt+1] + w02*s[0][cc][tt+2] + sb0;
    float x1v = w10*s[1][cc][tt] + w11*s[1][cc][tt+1] + w12*s[1][cc][tt+2] + sb1;
    float vv  = w20*s[2][cc][tt] + w21*s[2][cc][tt+1] + w22*s[2][cc][tt+2] + sb2;
    x0Out[ob + tt] = f2bf(x0v);
    gOut[ob + tt]  = f2bf(vv * x1v);
  }
}

// ---------------- FFT conv per (b,c): y = IDFT(DFT(g) .* Kf) ; z = (y + g*fb) * x0 ----------------
__global__ void k_fftconv(const u16* __restrict__ g, const u16* __restrict__ x0,
                          const float2* __restrict__ Kf, const float* __restrict__ fbias,
                          u16* __restrict__ z){
  int c = blockIdx.x, b = blockIdx.y;
  int tid = threadIdx.x;
  __shared__ float2 a[NFFT];
  const size_t rowoff = ((size_t)(b * DM + c)) * L_SEQ;
  float gv[8];
  for (int i = 0; i < 8; ++i){
    int t = tid + (i << 8);
    float gx = bf2f(g[rowoff + t]);
    gv[i] = gx;
    a[t] = make_float2(gx, 0.f);
    a[t + L_SEQ] = make_float2(0.f, 0.f);
  }
  __syncthreads();
  fft_dif(a, tid);
  const float2* kf = &Kf[(size_t)c * NFFT];
  for (int i = 0; i < 16; ++i){
    int idx = tid + (i << 8);
    float2 u = a[idx], k = kf[idx];
    a[idx] = make_float2(u.x*k.x - u.y*k.y, u.x*k.y + u.y*k.x);
  }
  __syncthreads();
  fft_dit_inv(a, tid);
  float fb = fbias[c];
  for (int i = 0; i < 8; ++i){
    int t = tid + (i << 8);
    float y = a[t].x + gv[i] * fb;
    float xv = bf2f(x0[rowoff + t]);
    z[rowoff + t] = f2bf(y * xv);
  }
}

// ---------------- transpose z: (b,d,l) bf16 -> (b,l,d) bf16 ----------------
__global__ void k_transpose_z(const u16* __restrict__ zin, u16* __restrict__ zout){
  __shared__ u16 tile[32][33];
  int l0 = blockIdx.x * 32, d0 = blockIdx.y * 32, b = blockIdx.z;
  int x = threadIdx.x, y = threadIdx.y;
  for (int i = 0; i < 4; ++i){
    int d = d0 + y + i*8;
    tile[y + i*8][x] = zin[((size_t)(b * DM + d)) * L_SEQ + l0 + x];
  }
  __syncthreads();
  for (int i = 0; i < 4; ++i){
    int l = l0 + y + i*8;
    zout[((size_t)(b * L_SEQ + l)) * DM + d0 + x] = tile[x][y + i*8];
  }
}

extern "C" void kernel_launch(void* const* d_in, const int* in_sizes, int n_in,
                              void* d_out, int out_size, void* d_ws, size_t ws_size,
                              hipStream_t stream){
  (void)in_sizes; (void)n_in; (void)out_size; (void)ws_size;
  const float* u       = (const float*)d_in[0];
  const float* in_w    = (const float*)d_in[1];
  const float* in_b    = (const float*)d_in[2];
  const float* short_w = (const float*)d_in[3];
  const float* short_b = (const float*)d_in[4];
  const float* w0 = (const float*)d_in[5];
  const float* b0 = (const float*)d_in[6];
  const float* f0 = (const float*)d_in[7];
  const float* w1 = (const float*)d_in[8];
  const float* b1 = (const float*)d_in[9];
  const float* f1 = (const float*)d_in[10];
  const float* w2 = (const float*)d_in[11];
  const float* b2 = (const float*)d_in[12];
  const float* f2 = (const float*)d_in[13];
  const float* w3 = (const float*)d_in[14];
  const float* fbias = (const float*)d_in[15];
  const float* out_w = (const float*)d_in[16];
  const float* out_b = (const float*)d_in[17];
  float* out = (float*)d_out;

  char* ws = (char*)d_ws;
  size_t off = 0;
  auto alloc = [&](size_t bytes)->void*{
    void* p = ws + off; off += (bytes + 255) & ~(size_t)255; return p;
  };
  const int M = BATCH * L_SEQ; // 8192
  u16*   u_bf  = (u16*)  alloc((size_t)M * DM * 2);       // later reused as z
  u16*   inwT  = (u16*)  alloc((size_t)TW * DM * 2);
  u16*   outwT = (u16*)  alloc((size_t)DM * DM * 2);
  float* H2    = (float*)alloc((size_t)L_SEQ * 64 * 4);
  float2* Kf   = (float2*)alloc((size_t)DM * NFFT * 8);
  u16*   up    = (u16*)  alloc((size_t)M * TW * 2);       // later reused as zT
  u16*   gbuf  = (u16*)  alloc((size_t)BATCH * DM * L_SEQ * 2);
  u16*   x0buf = (u16*)  alloc((size_t)BATCH * DM * L_SEQ * 2);
  u16*   z  = u_bf;   // alias: u_bf dead after gemm1
  u16*   zT = up;     // alias: up dead after shortconv

  k_convert_u<<<2048, 256, 0, stream>>>((const float4*)u, u_bf, (M * DM) / 4);
  k_transpose_w<<<dim3(TW/32, DM/32), dim3(32, 8), 0, stream>>>(in_w, inwT, DM, TW);
  k_transpose_w<<<dim3(DM/32, DM/32), dim3(32, 8), 0, stream>>>(out_w, outwT, DM, DM);
  k_filter_h2<<<L_SEQ, 64, 0, stream>>>(w0, b0, f0, w1, b1, f1, w2, b2, f2, H2);
  k_filter_fft<<<DM, 256, 0, stream>>>(H2, w3, Kf);
  k_gemm<true><<<dim3(TW/128, M/128), 256, 0, stream>>>(u_bf, inwT, in_b, up, M, TW, DM);
  k_shortconv<<<dim3(L_SEQ/128, DM/32, BATCH), 256, 0, stream>>>(up, short_w, short_b, gbuf, x0buf);
  k_fftconv<<<dim3(DM, BATCH), 256, 0, stream>>>(gbuf, x0buf, Kf, fbias, z);
  k_transpose_z<<<dim3(L_SEQ/32, DM/32, BATCH), dim3(32, 8), 0, stream>>>(z, zT);
  k_gemm<false><<<dim3(DM/128, M/128), 256, 0, stream>>>(zT, outwT, out_b, out, M, DM, DM);
}

// Round 2
// 333.291 us; speedup vs baseline: 1.3019x; 1.3019x over previous
//
#include <hip/hip_runtime.h>
#include <stdint.h>

typedef unsigned short u16;
typedef __attribute__((ext_vector_type(8))) short short8;
typedef __attribute__((ext_vector_type(4))) float f32x4;

#define PI_F 3.14159265358979323846f
#define L_SEQ 2048
#define NFFT 4096
#define DM 1024
#define TW 3072
#define BATCH 4
#define KFS 2064   // per-channel half-spectrum stride (2049 used, padded)

__device__ __forceinline__ u16 f2bf(float f){
  union { float f; uint32_t u; } v; v.f = f;
  uint32_t r = v.u + 0x7fffu + ((v.u >> 16) & 1u);
  return (u16)(r >> 16);
}
__device__ __forceinline__ float bf2f(u16 h){
  union { uint32_t u; float f; } v; v.u = ((uint32_t)h) << 16;
  return v.f;
}

__device__ __forceinline__ void async16(const void* g, void* l){
  __builtin_amdgcn_global_load_lds(
      (const __attribute__((address_space(1))) void*)g,
      (__attribute__((address_space(3))) void*)l, 16, 0, 0);
}

// hardware sin/cos, input in REVOLUTIONS (angle = 2*pi*rev)
__device__ __forceinline__ void sincos_rev(float rev, float& sn, float& cs){
  asm("v_sin_f32 %0, %1" : "=v"(sn) : "v"(rev));
  asm("v_cos_f32 %0, %1" : "=v"(cs) : "v"(rev));
}

// padded LDS index: +1 float2 per 32 to break power-of-2 bank strides
__device__ __forceinline__ int P(int i){ return i + (i >> 5); }
// bit-reverse of a 12-bit index
__device__ __forceinline__ int brv12(int k){ return (int)(__brev((unsigned)k) >> 20); }

// ---------------- convert u (fp32 -> bf16), vectorized ----------------
__global__ void k_convert_u(const float4* __restrict__ in, u16* __restrict__ outp, int n4){
  int idx = blockIdx.x * blockDim.x + threadIdx.x;
  int stride = gridDim.x * blockDim.x;
  for (int i = idx; i < n4; i += stride){
    float4 v = in[i];
    u16 r0 = f2bf(v.x), r1 = f2bf(v.y), r2 = f2bf(v.z), r3 = f2bf(v.w);
    u16* o = outp + (size_t)i * 4;
    o[0] = r0; o[1] = r1; o[2] = r2; o[3] = r3;
  }
}

// ---------------- transpose weight fp32 (K,N) -> bf16 (N,K) ----------------
__global__ void k_transpose_w(const float* __restrict__ in, u16* __restrict__ outp, int K, int N){
  __shared__ float tile[32][33];
  int n0 = blockIdx.x * 32, k0 = blockIdx.y * 32;
  int x = threadIdx.x, y = threadIdx.y;
  for (int i = 0; i < 4; ++i)
    tile[y + i*8][x] = in[(size_t)(k0 + y + i*8) * N + n0 + x];
  __syncthreads();
  for (int i = 0; i < 4; ++i)
    outp[(size_t)(n0 + y + i*8) * K + k0 + x] = f2bf(tile[x][y + i*8]);
}

// ---------------- filter MLP: H2 (2048 x 64) ----------------
__global__ void k_filter_h2(const float* __restrict__ w0, const float* __restrict__ b0, const float* __restrict__ f0,
                            const float* __restrict__ w1, const float* __restrict__ b1, const float* __restrict__ f1,
                            const float* __restrict__ w2, const float* __restrict__ b2, const float* __restrict__ f2,
                            float* __restrict__ H2){
  int t = blockIdx.x;
  int j = threadIdx.x; // 0..63
  float tn = t * (1.0f / 2047.0f);
  float ph = 1e-4f * 2.0f * PI_F * (float)t * (1.0f / 2048.0f);
  float z0 = tn, z1 = cosf(ph), z2 = -sinf(ph);
  __shared__ float hs[64];
  float pre = z0 * w0[j] + z1 * w0[64 + j] + z2 * w0[128 + j] + b0[j];
  float h = sinf(f0[j] * pre);
  hs[j] = h;
  __syncthreads();
  float acc = b1[j];
  for (int i = 0; i < 64; ++i) acc += hs[i] * w1[i*64 + j];
  h = sinf(f1[j] * acc);
  __syncthreads();
  hs[j] = h;
  __syncthreads();
  acc = b2[j];
  for (int i = 0; i < 64; ++i) acc += hs[i] * w2[i*64 + j];
  h = sinf(f2[j] * acc);
  H2[t*64 + j] = h;
}

// ---------------- FFT stages on padded LDS (4096-pt, first/last stage fused by callers) ----
// forward DIF stages p=11..1: (two independent 2048 halves) natural-in -> bit-rev-out
__device__ __forceinline__ void fft_fwd_stages(float2* a, int tid){
  for (int p = 11; p >= 1; --p){
    int half = 1 << (p - 1);
    float nscale = -1.0f / (float)(1 << p);
    #pragma unroll 2
    for (int i = 0; i < 8; ++i){
      int bfi = tid + (i << 8);
      int j = bfi & (half - 1);
      int i0 = bfi + (bfi & ~(half - 1));
      int i1 = i0 + half;
      float2 u = a[P(i0)], v = a[P(i1)];
      float sn, cs; sincos_rev(nscale * (float)j, sn, cs);
      float dx = u.x - v.x, dy = u.y - v.y;
      a[P(i0)] = make_float2(u.x + v.x, u.y + v.y);
      a[P(i1)] = make_float2(dx*cs - dy*sn, dx*sn + dy*cs);
    }
    __syncthreads();
  }
}
// inverse DIT stages p=1..11: bit-rev-in -> natural (within halves); caller fuses p=12
__device__ __forceinline__ void fft_inv_stages(float2* a, int tid){
  for (int p = 1; p <= 11; ++p){
    int half = 1 << (p - 1);
    float pscale = 1.0f / (float)(1 << p);
    #pragma unroll 2
    for (int i = 0; i < 8; ++i){
      int bfi = tid + (i << 8);
      int j = bfi & (half - 1);
      int i0 = bfi + (bfi & ~(half - 1));
      int i1 = i0 + half;
      float2 u = a[P(i0)], v = a[P(i1)];
      float sn, cs; sincos_rev(pscale * (float)j, sn, cs);
      float tx = v.x*cs - v.y*sn, ty = v.x*sn + v.y*cs;
      a[P(i0)] = make_float2(u.x + tx, u.y + ty);
      a[P(i1)] = make_float2(u.x - tx, u.y - ty);
    }
    __syncthreads();
  }
}

// ---------------- filter spectra, 2 channels packed per FFT ----------------
// Kf[c][k] for k=0..2048 natural order, scaled by 1/NFFT
__global__ void k_filter_fft(const float* __restrict__ H2, const float* __restrict__ w3,
                             float2* __restrict__ Kf){
  int c0 = blockIdx.x * 2, c1 = c0 + 1;
  int tid = threadIdx.x;
  __shared__ float2 a[4224];
  __shared__ float wcol[2][64];
  if (tid < 64){ wcol[0][tid] = w3[tid * DM + c0]; wcol[1][tid] = w3[tid * DM + c1]; }
  __syncthreads();
  float absd0 = 3.070113457325394f + 12.280453829301576f * ((float)c0 * (1.0f / 1023.0f));
  float absd1 = 3.070113457325394f + 12.280453829301576f * ((float)c1 * (1.0f / 1023.0f));
  for (int i = 0; i < 8; ++i){
    int t = tid + (i << 8);
    const float* hr = &H2[t * 64];
    float s0 = 0.f, s1 = 0.f;
    #pragma unroll 8
    for (int j = 0; j < 64; ++j){ float h = hr[j]; s0 += h * wcol[0][j]; s1 += h * wcol[1][j]; }
    float tn = (float)t * (1.0f / 2047.0f);
    float k0v = s0 * __expf(-tn * absd0);
    float k1v = s1 * __expf(-tn * absd1);
    // fused first DIF stage (upper half of input is zero)
    float sn, cs; sincos_rev((float)t * (-1.0f / 4096.0f), sn, cs);
    a[P(t)] = make_float2(k0v, k1v);
    a[P(t + L_SEQ)] = make_float2(k0v*cs - k1v*sn, k0v*sn + k1v*cs);
  }
  __syncthreads();
  fft_fwd_stages(a, tid);
  const float inv = 1.0f / (float)NFFT;
  float2* kf0 = &Kf[(size_t)c0 * KFS];
  float2* kf1 = kf0 + KFS;
  for (int i = 0; i < 8; ++i){
    int k = tid + (i << 8);
    int m = (NFFT - k) & (NFFT - 1);
    float2 Zk = a[P(brv12(k))], Zm = a[P(brv12(m))];
    float gar = 0.5f*(Zk.x + Zm.x), gai = 0.5f*(Zk.y - Zm.y);
    float gbr = 0.5f*(Zk.y + Zm.y), gbi = 0.5f*(Zm.x - Zk.x);
    kf0[k] = make_float2(gar*inv, gai*inv);
    kf1[k] = make_float2(gbr*inv, gbi*inv);
    if (k == 0){ // Nyquist bin
      float2 Zn = a[P(1)];
      kf0[2048] = make_float2(Zn.x*inv, 0.f);
      kf1[2048] = make_float2(Zn.y*inv, 0.f);
    }
  }
}

// ---------------- GEMM: C(M,N) = A(M,K)bf16 * Bt(N,K)bf16^T + bias ----------------
template<bool OUT_BF16>
__global__ __launch_bounds__(256) void k_gemm(const u16* __restrict__ A, const u16* __restrict__ Bt,
                                              const float* __restrict__ bias, void* __restrict__ Cout,
                                              int M, int N, int K){
  __shared__ __align__(16) u16 As[128 * 32];
  __shared__ __align__(16) u16 Bs[128 * 32];
  int m0 = blockIdx.y * 128;
  int n0 = blockIdx.x * 128;
  int tid = threadIdx.x;
  int wave = tid >> 6, lane = tid & 63;
  int wm = wave >> 1, wn = wave & 1;
  f32x4 acc[4][4] = {};
  int lrow = lane & 15;
  int lk = (lane >> 4) * 8;
  int ksteps = K >> 5;
  for (int kt = 0; kt < ksteps; ++kt){
    int k0 = kt << 5;
    #pragma unroll
    for (int half = 0; half < 2; ++half){
      int row = wave * 32 + half * 16 + (lane >> 2);
      int chunk = (lane & 3) * 8;
      async16(A + (size_t)(m0 + row) * K + k0 + chunk, &As[(wave*32 + half*16) * 32]);
      async16(Bt + (size_t)(n0 + row) * K + k0 + chunk, &Bs[(wave*32 + half*16) * 32]);
    }
    __syncthreads();
    short8 af[4], bfr[4];
    #pragma unroll
    for (int i = 0; i < 4; ++i){
      af[i]  = *(const short8*)&As[(wm*64 + i*16 + lrow) * 32 + lk];
      bfr[i] = *(const short8*)&Bs[(wn*64 + i*16 + lrow) * 32 + lk];
    }
    #pragma unroll
    for (int i = 0; i < 4; ++i)
      #pragma unroll
      for (int j = 0; j < 4; ++j)
        acc[i][j] = __builtin_amdgcn_mfma_f32_16x16x32_bf16(af[i], bfr[j], acc[i][j], 0, 0, 0);
    __syncthreads();
  }
  #pragma unroll
  for (int j = 0; j < 4; ++j){
    int col = n0 + wn*64 + j*16 + (lane & 15);
    float bv = bias[col];
    #pragma unroll
    for (int i = 0; i < 4; ++i){
      int rbase = m0 + wm*64 + i*16 + (lane >> 4) * 4;
      #pragma unroll
      for (int r = 0; r < 4; ++r){
        float val = acc[i][j][r] + bv;
        if (OUT_BF16) ((u16*)Cout)[(size_t)(rbase + r) * N + col] = f2bf(val);
        else ((float*)Cout)[(size_t)(rbase + r) * N + col] = val;
      }
    }
  }
}

// ---------------- short conv + gate + transpose to (b,d,l) ----------------
__global__ void k_shortconv(const u16* __restrict__ up, const float* __restrict__ sw,
                            const float* __restrict__ sb,
                            u16* __restrict__ gOut, u16* __restrict__ x0Out){
  __shared__ float s[3][32][130];
  int t0 = blockIdx.x * 128;
  int c0 = blockIdx.y * 32;
  int b  = blockIdx.z;
  int tid = threadIdx.x;
  int cc = tid & 31, rr = tid >> 5;
  for (int g2 = 0; g2 < 3; ++g2){
    for (int r = rr; r < 130; r += 8){
      int t = t0 + r - 2;
      float v = 0.f;
      if (t >= 0) v = bf2f(up[((size_t)(b * L_SEQ + t)) * TW + g2 * DM + c0 + cc]);
      s[g2][cc][r] = v;
    }
  }
  __syncthreads();
  int cglob = c0 + cc;
  float w00 = sw[cglob*3+0],        w01 = sw[cglob*3+1],        w02 = sw[cglob*3+2];
  float w10 = sw[(DM+cglob)*3+0],   w11 = sw[(DM+cglob)*3+1],   w12 = sw[(DM+cglob)*3+2];
  float w20 = sw[(2*DM+cglob)*3+0], w21 = sw[(2*DM+cglob)*3+1], w22 = sw[(2*DM+cglob)*3+2];
  float sb0 = sb[cglob], sb1 = sb[DM+cglob], sb2 = sb[2*DM+cglob];
  size_t ob = ((size_t)(b * DM + cglob)) * L_SEQ + t0;
  for (int q = 0; q < 16; ++q){
    int tt = rr * 16 + q;
    float x0v = w00*s[0][cc][tt] + w01*s[0][cc][tt+1] + w02*s[0][cc][tt+2] + sb0;
    float x1v = w10*s[1][cc][tt] + w11*s[1][cc][tt+1] + w12*s[1][cc][tt+2] + sb1;
    float vv  = w20*s[2][cc][tt] + w21*s[2][cc][tt+1] + w22*s[2][cc][tt+2] + sb2;
    x0Out[ob + tt] = f2bf(x0v);
    gOut[ob + tt]  = f2bf(vv * x1v);
  }
}

// ---------------- FFT conv, 2 channels packed per block ----------------
__global__ __launch_bounds__(256) void k_fftconv(const u16* __restrict__ g, const u16* __restrict__ x0,
                          const float2* __restrict__ Kf, const float* __restrict__ fbias,
                          u16* __restrict__ z){
  int c0 = blockIdx.x * 2, c1 = c0 + 1;
  int b = blockIdx.y;
  int tid = threadIdx.x;
  __shared__ float2 a[4224];
  const size_t row0 = ((size_t)(b * DM + c0)) * L_SEQ;
  const size_t row1 = row0 + L_SEQ;
  float gv0[8], gv1[8];
  // load + fused first DIF stage (upper half zero)
  for (int i = 0; i < 8; ++i){
    int t = tid + (i << 8);
    float g0 = bf2f(g[row0 + t]);
    float g1 = bf2f(g[row1 + t]);
    gv0[i] = g0; gv1[i] = g1;
    float sn, cs; sincos_rev((float)t * (-1.0f / 4096.0f), sn, cs);
    a[P(t)] = make_float2(g0, g1);
    a[P(t + L_SEQ)] = make_float2(g0*cs - g1*sn, g0*sn + g1*cs);
  }
  __syncthreads();
  fft_fwd_stages(a, tid);
  // pointwise: unpack 2 real spectra, multiply, repack
  const float2* kf0 = &Kf[(size_t)c0 * KFS];
  const float2* kf1 = kf0 + KFS;
  for (int i = 0; i < 8; ++i){
    int k = tid + (i << 8);
    int m = (NFFT - k) & (NFFT - 1);
    int sk = P(brv12(k)), sm = P(brv12(m));
    float2 Zk = a[sk], Zm = a[sm];
    float2 K0 = kf0[k], K1 = kf1[k];
    float gar = 0.5f*(Zk.x + Zm.x), gai = 0.5f*(Zk.y - Zm.y);
    float gbr = 0.5f*(Zk.y + Zm.y), gbi = 0.5f*(Zm.x - Zk.x);
    float yar = gar*K0.x - gai*K0.y, yai = gar*K0.y + gai*K0.x;
    float ybr = gbr*K1.x - gbi*K1.y, ybi = gbr*K1.y + gbi*K1.x;
    a[sk] = make_float2(yar - ybi, yai + ybr);
    if (k == 0){ // Nyquist (self-paired, as is k=0)
      float2 Zn = a[P(1)];
      float2 Kn0 = kf0[2048], Kn1 = kf1[2048];
      float nar = Zn.x*Kn0.x, nai = Zn.x*Kn0.y;
      float nbr = Zn.y*Kn1.x, nbi = Zn.y*Kn1.y;
      a[P(1)] = make_float2(nar - nbi, nai + nbr);
    } else {
      a[sm] = make_float2(yar + ybi, ybr - yai);
    }
  }
  __syncthreads();
  fft_inv_stages(a, tid);
  // fused last inverse stage (only lower half needed) + gate + store
  float fb0 = fbias[c0], fb1 = fbias[c1];
  for (int i = 0; i < 8; ++i){
    int t = tid + (i << 8);
    float2 u = a[P(t)], v = a[P(t + L_SEQ)];
    float sn, cs; sincos_rev((float)t * (1.0f / 4096.0f), sn, cs);
    float tx = v.x*cs - v.y*sn, ty = v.x*sn + v.y*cs;
    float y0 = u.x + tx, y1 = u.y + ty;
    float z0v = (y0 + gv0[i]*fb0) * bf2f(x0[row0 + t]);
    float z1v = (y1 + gv1[i]*fb1) * bf2f(x0[row1 + t]);
    z[row0 + t] = f2bf(z0v);
    z[row1 + t] = f2bf(z1v);
  }
}

// ---------------- transpose z: (b,d,l) bf16 -> (b,l,d) bf16 ----------------
__global__ void k_transpose_z(const u16* __restrict__ zin, u16* __restrict__ zout){
  __shared__ u16 tile[32][33];
  int l0 = blockIdx.x * 32, d0 = blockIdx.y * 32, b = blockIdx.z;
  int x = threadIdx.x, y = threadIdx.y;
  for (int i = 0; i < 4; ++i){
    int d = d0 + y + i*8;
    tile[y + i*8][x] = zin[((size_t)(b * DM + d)) * L_SEQ + l0 + x];
  }
  __syncthreads();
  for (int i = 0; i < 4; ++i){
    int l = l0 + y + i*8;
    zout[((size_t)(b * L_SEQ + l)) * DM + d0 + x] = tile[x][y + i*8];
  }
}

extern "C" void kernel_launch(void* const* d_in, const int* in_sizes, int n_in,
                              void* d_out, int out_size, void* d_ws, size_t ws_size,
                              hipStream_t stream){
  (void)in_sizes; (void)n_in; (void)out_size; (void)ws_size;
  const float* u       = (const float*)d_in[0];
  const float* in_w    = (const float*)d_in[1];
  const float* in_b    = (const float*)d_in[2];
  const float* short_w = (const float*)d_in[3];
  const float* short_b = (const float*)d_in[4];
  const float* w0 = (const float*)d_in[5];
  const float* b0 = (const float*)d_in[6];
  const float* f0 = (const float*)d_in[7];
  const float* w1 = (const float*)d_in[8];
  const float* b1 = (const float*)d_in[9];
  const float* f1 = (const float*)d_in[10];
  const float* w2 = (const float*)d_in[11];
  const float* b2 = (const float*)d_in[12];
  const float* f2 = (const float*)d_in[13];
  const float* w3 = (const float*)d_in[14];
  const float* fbias = (const float*)d_in[15];
  const float* out_w = (const float*)d_in[16];
  const float* out_b = (const float*)d_in[17];
  float* out = (float*)d_out;

  char* ws = (char*)d_ws;
  size_t off = 0;
  auto alloc = [&](size_t bytes)->void*{
    void* p = ws + off; off += (bytes + 255) & ~(size_t)255; return p;
  };
  const int M = BATCH * L_SEQ; // 8192
  u16*   u_bf  = (u16*)  alloc((size_t)M * DM * 2);       // later reused as z
  u16*   inwT  = (u16*)  alloc((size_t)TW * DM * 2);
  u16*   outwT = (u16*)  alloc((size_t)DM * DM * 2);
  float* H2    = (float*)alloc((size_t)L_SEQ * 64 * 4);
  float2* Kf   = (float2*)alloc((size_t)DM * KFS * 8);
  u16*   up    = (u16*)  alloc((size_t)M * TW * 2);       // later reused as zT
  u16*   gbuf  = (u16*)  alloc((size_t)BATCH * DM * L_SEQ * 2);
  u16*   x0buf = (u16*)  alloc((size_t)BATCH * DM * L_SEQ * 2);
  u16*   z  = u_bf;   // alias: u_bf dead after gemm1
  u16*   zT = up;     // alias: up dead after shortconv

  k_convert_u<<<2048, 256, 0, stream>>>((const float4*)u, u_bf, (M * DM) / 4);
  k_transpose_w<<<dim3(TW/32, DM/32), dim3(32, 8), 0, stream>>>(in_w, inwT, DM, TW);
  k_transpose_w<<<dim3(DM/32, DM/32), dim3(32, 8), 0, stream>>>(out_w, outwT, DM, DM);
  k_filter_h2<<<L_SEQ, 64, 0, stream>>>(w0, b0, f0, w1, b1, f1, w2, b2, f2, H2);
  k_filter_fft<<<DM/2, 256, 0, stream>>>(H2, w3, Kf);
  k_gemm<true><<<dim3(TW/128, M/128), 256, 0, stream>>>(u_bf, inwT, in_b, up, M, TW, DM);
  k_shortconv<<<dim3(L_SEQ/128, DM/32, BATCH), 256, 0, stream>>>(up, short_w, short_b, gbuf, x0buf);
  k_fftconv<<<dim3(DM/2, BATCH), 256, 0, stream>>>(gbuf, x0buf, Kf, fbias, z);
  k_transpose_z<<<dim3(L_SEQ/32, DM/32, BATCH), dim3(32, 8), 0, stream>>>(z, zT);
  k_gemm<false><<<dim3(DM/128, M/128), 256, 0, stream>>>(zT, outwT, out_b, out, M, DM, DM);
}

// Round 3
// 283.723 us; speedup vs baseline: 1.5293x; 1.1747x over previous
//
#include <hip/hip_runtime.h>
#include <stdint.h>

typedef unsigned short u16;
typedef __attribute__((ext_vector_type(8))) short short8;
typedef __attribute__((ext_vector_type(4))) float f32x4;

#define PI_F 3.14159265358979323846f
#define L_SEQ 2048
#define NFFT 4096
#define DM 1024
#define TW 3072
#define BATCH 4

__device__ __forceinline__ u16 f2bf(float f){
  union { float f; uint32_t u; } v; v.f = f;
  uint32_t r = v.u + 0x7fffu + ((v.u >> 16) & 1u);
  return (u16)(r >> 16);
}
__device__ __forceinline__ float bf2f(u16 h){
  union { uint32_t u; float f; } v; v.u = ((uint32_t)h) << 16;
  return v.f;
}

__device__ __forceinline__ void async16(const void* g, void* l){
  __builtin_amdgcn_global_load_lds(
      (const __attribute__((address_space(1))) void*)g,
      (__attribute__((address_space(3))) void*)l, 16, 0, 0);
}

// hardware sin/cos, input in REVOLUTIONS (angle = 2*pi*rev)
__device__ __forceinline__ void sincos_rev(float rev, float& sn, float& cs){
  asm("v_sin_f32 %0, %1" : "=v"(sn) : "v"(rev));
  asm("v_cos_f32 %0, %1" : "=v"(cs) : "v"(rev));
}

__device__ __forceinline__ float2 cmulf(float2 a, float c, float s){
  return make_float2(a.x*c - a.y*s, a.x*s + a.y*c);
}

// old pad (filter_fft path only)
__device__ __forceinline__ int Pold(int i){ return i + (i >> 5); }
// new pad for the 3-phase FFT: +1 float2 per 16 — gives minimal 4 dwords/bank
// for every access class (verified per-pattern: stage R/W, Z exchange)
__device__ __forceinline__ int P16(int i){ return i + (i >> 4); }
__device__ __forceinline__ int brv12(int k){ return (int)(__brev((unsigned)k) >> 20); }

// natural-order output k of radix-2 DIF FFT16 sits at a[BR4[k]]
__device__ static constexpr int BR4[16] = {0,8,4,12,2,10,6,14,1,9,5,13,3,11,7,15};

// in-register 16-point FFT, radix-2 DIF. SGN=+1: W=e^{-2pi i/16} (forward);
// SGN=-1: inverse (unscaled). Output bit-reversed: X[k] = a[BR4[k]].
template<int SGN>
__device__ __forceinline__ void fft16(float2* a){
  const float s = (float)SGN;
  static constexpr float tc[8]  = {1.f, 0.92387953f, 0.70710678f, 0.38268343f,
                                   0.f, -0.38268343f, -0.70710678f, -0.92387953f};
  static constexpr float ts_[8] = {0.f, -0.38268343f, -0.70710678f, -0.92387953f,
                                   -1.f, -0.92387953f, -0.70710678f, -0.38268343f};
  #pragma unroll
  for (int j = 0; j < 8; ++j){
    float2 u = a[j], v = a[j+8];
    float2 d = make_float2(u.x - v.x, u.y - v.y);
    a[j] = make_float2(u.x + v.x, u.y + v.y);
    a[j+8] = cmulf(d, tc[j], s*ts_[j]);
  }
  #pragma unroll
  for (int g = 0; g < 2; ++g){
    int b = g*8;
    #pragma unroll
    for (int j = 0; j < 4; ++j){
      float2 u = a[b+j], v = a[b+j+4];
      float2 d = make_float2(u.x - v.x, u.y - v.y);
      a[b+j] = make_float2(u.x + v.x, u.y + v.y);
      a[b+j+4] = cmulf(d, tc[2*j], s*ts_[2*j]);
    }
  }
  #pragma unroll
  for (int g = 0; g < 4; ++g){
    int b = g*4;
    #pragma unroll
    for (int j = 0; j < 2; ++j){
      float2 u = a[b+j], v = a[b+j+2];
      float2 d = make_float2(u.x - v.x, u.y - v.y);
      a[b+j] = make_float2(u.x + v.x, u.y + v.y);
      a[b+j+2] = (j == 0) ? d : cmulf(d, 0.f, -s);
    }
  }
  #pragma unroll
  for (int g = 0; g < 8; ++g){
    int b = g*2;
    float2 u = a[b], v = a[b+1];
    a[b] = make_float2(u.x + v.x, u.y + v.y);
    a[b+1] = make_float2(u.x - v.x, u.y - v.y);
  }
}

// ---------------- convert u (fp32 -> bf16), vectorized ----------------
__global__ void k_convert_u(const float4* __restrict__ in, u16* __restrict__ outp, int n4){
  int idx = blockIdx.x * blockDim.x + threadIdx.x;
  int stride = gridDim.x * blockDim.x;
  for (int i = idx; i < n4; i += stride){
    float4 v = in[i];
    u16 r0 = f2bf(v.x), r1 = f2bf(v.y), r2 = f2bf(v.z), r3 = f2bf(v.w);
    u16* o = outp + (size_t)i * 4;
    o[0] = r0; o[1] = r1; o[2] = r2; o[3] = r3;
  }
}

// ---------------- transpose weight fp32 (K,N) -> bf16 (N,K) ----------------
__global__ void k_transpose_w(const float* __restrict__ in, u16* __restrict__ outp, int K, int N){
  __shared__ float tile[32][33];
  int n0 = blockIdx.x * 32, k0 = blockIdx.y * 32;
  int x = threadIdx.x, y = threadIdx.y;
  for (int i = 0; i < 4; ++i)
    tile[y + i*8][x] = in[(size_t)(k0 + y + i*8) * N + n0 + x];
  __syncthreads();
  for (int i = 0; i < 4; ++i)
    outp[(size_t)(n0 + y + i*8) * K + k0 + x] = f2bf(tile[x][y + i*8]);
}

// ---------------- filter MLP: H2 (2048 x 64) ----------------
__global__ void k_filter_h2(const float* __restrict__ w0, const float* __restrict__ b0, const float* __restrict__ f0,
                            const float* __restrict__ w1, const float* __restrict__ b1, const float* __restrict__ f1,
                            const float* __restrict__ w2, const float* __restrict__ b2, const float* __restrict__ f2,
                            float* __restrict__ H2){
  int t = blockIdx.x;
  int j = threadIdx.x; // 0..63
  float tn = t * (1.0f / 2047.0f);
  float ph = 1e-4f * 2.0f * PI_F * (float)t * (1.0f / 2048.0f);
  float z0 = tn, z1 = cosf(ph), z2 = -sinf(ph);
  __shared__ float hs[64];
  float pre = z0 * w0[j] + z1 * w0[64 + j] + z2 * w0[128 + j] + b0[j];
  float h = sinf(f0[j] * pre);
  hs[j] = h;
  __syncthreads();
  float acc = b1[j];
  for (int i = 0; i < 64; ++i) acc += hs[i] * w1[i*64 + j];
  h = sinf(f1[j] * acc);
  __syncthreads();
  hs[j] = h;
  __syncthreads();
  acc = b2[j];
  for (int i = 0; i < 64; ++i) acc += hs[i] * w2[i*64 + j];
  h = sinf(f2[j] * acc);
  H2[t*64 + j] = h;
}

// ---------------- old-style forward stages (filter precompute only) ----------
__device__ __forceinline__ void fft_fwd_stages(float2* a, int tid){
  for (int p = 11; p >= 1; --p){
    int half = 1 << (p - 1);
    float nscale = -1.0f / (float)(1 << p);
    #pragma unroll 2
    for (int i = 0; i < 8; ++i){
      int bfi = tid + (i << 8);
      int j = bfi & (half - 1);
      int i0 = bfi + (bfi & ~(half - 1));
      int i1 = i0 + half;
      float2 u = a[Pold(i0)], v = a[Pold(i1)];
      float sn, cs; sincos_rev(nscale * (float)j, sn, cs);
      float dx = u.x - v.x, dy = u.y - v.y;
      a[Pold(i0)] = make_float2(u.x + v.x, u.y + v.y);
      a[Pold(i1)] = make_float2(dx*cs - dy*sn, dx*sn + dy*cs);
    }
    __syncthreads();
  }
}

// ---------------- filter spectra, 2 channels packed per FFT ----------------
// Kf[c][k] FULL table k=0..4095, natural order, scaled by 1/NFFT
__global__ void k_filter_fft(const float* __restrict__ H2, const float* __restrict__ w3,
                             float2* __restrict__ Kf){
  int c0 = blockIdx.x * 2, c1 = c0 + 1;
  int tid = threadIdx.x;
  __shared__ float2 a[4224];
  __shared__ float wcol[2][64];
  if (tid < 64){ wcol[0][tid] = w3[tid * DM + c0]; wcol[1][tid] = w3[tid * DM + c1]; }
  __syncthreads();
  float absd0 = 3.070113457325394f + 12.280453829301576f * ((float)c0 * (1.0f / 1023.0f));
  float absd1 = 3.070113457325394f + 12.280453829301576f * ((float)c1 * (1.0f / 1023.0f));
  for (int i = 0; i < 8; ++i){
    int t = tid + (i << 8);
    const float* hr = &H2[t * 64];
    float s0 = 0.f, s1 = 0.f;
    #pragma unroll 8
    for (int j = 0; j < 64; ++j){ float h = hr[j]; s0 += h * wcol[0][j]; s1 += h * wcol[1][j]; }
    float tn = (float)t * (1.0f / 2047.0f);
    float k0v = s0 * __expf(-tn * absd0);
    float k1v = s1 * __expf(-tn * absd1);
    float sn, cs; sincos_rev((float)t * (-1.0f / 4096.0f), sn, cs);
    a[Pold(t)] = make_float2(k0v, k1v);
    a[Pold(t + L_SEQ)] = make_float2(k0v*cs - k1v*sn, k0v*sn + k1v*cs);
  }
  __syncthreads();
  fft_fwd_stages(a, tid);
  const float inv = 1.0f / (float)NFFT;
  float2* kf0 = &Kf[(size_t)c0 * NFFT];
  float2* kf1 = kf0 + NFFT;
  for (int i = 0; i < 8; ++i){
    int k = tid + (i << 8);
    int m = (NFFT - k) & (NFFT - 1);
    float2 Zk = a[Pold(brv12(k))], Zm = a[Pold(brv12(m))];
    float gar = 0.5f*(Zk.x + Zm.x), gai = 0.5f*(Zk.y - Zm.y);
    float gbr = 0.5f*(Zk.y + Zm.y), gbi = 0.5f*(Zm.x - Zk.x);
    kf0[k] = make_float2(gar*inv, gai*inv);
    kf1[k] = make_float2(gbr*inv, gbi*inv);
    if (k > 0){
      kf0[NFFT - k] = make_float2(gar*inv, -gai*inv);
      kf1[NFFT - k] = make_float2(gbr*inv, -gbi*inv);
    } else { // Nyquist bin (brv12(2048) == 1)
      float2 Zn = a[Pold(1)];
      kf0[2048] = make_float2(Zn.x*inv, 0.f);
      kf1[2048] = make_float2(Zn.y*inv, 0.f);
    }
  }
}

// ---------------- GEMM: C(M,N) = A(M,K)bf16 * Bt(N,K)bf16^T + bias ----------------
template<bool OUT_BF16>
__global__ __launch_bounds__(256) void k_gemm(const u16* __restrict__ A, const u16* __restrict__ Bt,
                                              const float* __restrict__ bias, void* __restrict__ Cout,
                                              int M, int N, int K){
  __shared__ __align__(16) u16 As[128 * 32];
  __shared__ __align__(16) u16 Bs[128 * 32];
  int m0 = blockIdx.y * 128;
  int n0 = blockIdx.x * 128;
  int tid = threadIdx.x;
  int wave = tid >> 6, lane = tid & 63;
  int wm = wave >> 1, wn = wave & 1;
  f32x4 acc[4][4] = {};
  int lrow = lane & 15;
  int lk = (lane >> 4) * 8;
  int ksteps = K >> 5;
  for (int kt = 0; kt < ksteps; ++kt){
    int k0 = kt << 5;
    #pragma unroll
    for (int half = 0; half < 2; ++half){
      int row = wave * 32 + half * 16 + (lane >> 2);
      int chunk = (lane & 3) * 8;
      async16(A + (size_t)(m0 + row) * K + k0 + chunk, &As[(wave*32 + half*16) * 32]);
      async16(Bt + (size_t)(n0 + row) * K + k0 + chunk, &Bs[(wave*32 + half*16) * 32]);
    }
    __syncthreads();
    short8 af[4], bfr[4];
    #pragma unroll
    for (int i = 0; i < 4; ++i){
      af[i]  = *(const short8*)&As[(wm*64 + i*16 + lrow) * 32 + lk];
      bfr[i] = *(const short8*)&Bs[(wn*64 + i*16 + lrow) * 32 + lk];
    }
    #pragma unroll
    for (int i = 0; i < 4; ++i)
      #pragma unroll
      for (int j = 0; j < 4; ++j)
        acc[i][j] = __builtin_amdgcn_mfma_f32_16x16x32_bf16(af[i], bfr[j], acc[i][j], 0, 0, 0);
    __syncthreads();
  }
  #pragma unroll
  for (int j = 0; j < 4; ++j){
    int col = n0 + wn*64 + j*16 + (lane & 15);
    float bv = bias[col];
    #pragma unroll
    for (int i = 0; i < 4; ++i){
      int rbase = m0 + wm*64 + i*16 + (lane >> 4) * 4;
      #pragma unroll
      for (int r = 0; r < 4; ++r){
        float val = acc[i][j][r] + bv;
        if (OUT_BF16) ((u16*)Cout)[(size_t)(rbase + r) * N + col] = f2bf(val);
        else ((float*)Cout)[(size_t)(rbase + r) * N + col] = val;
      }
    }
  }
}

// ---------------- short conv + gate + transpose to (b,d,l) ----------------
__global__ void k_shortconv(const u16* __restrict__ up, const float* __restrict__ sw,
                            const float* __restrict__ sb,
                            u16* __restrict__ gOut, u16* __restrict__ x0Out){
  __shared__ float s[3][32][130];
  int t0 = blockIdx.x * 128;
  int c0 = blockIdx.y * 32;
  int b  = blockIdx.z;
  int tid = threadIdx.x;
  int cc = tid & 31, rr = tid >> 5;
  for (int g2 = 0; g2 < 3; ++g2){
    for (int r = rr; r < 130; r += 8){
      int t = t0 + r - 2;
      float v = 0.f;
      if (t >= 0) v = bf2f(up[((size_t)(b * L_SEQ + t)) * TW + g2 * DM + c0 + cc]);
      s[g2][cc][r] = v;
    }
  }
  __syncthreads();
  int cglob = c0 + cc;
  float w00 = sw[cglob*3+0],        w01 = sw[cglob*3+1],        w02 = sw[cglob*3+2];
  float w10 = sw[(DM+cglob)*3+0],   w11 = sw[(DM+cglob)*3+1],   w12 = sw[(DM+cglob)*3+2];
  float w20 = sw[(2*DM+cglob)*3+0], w21 = sw[(2*DM+cglob)*3+1], w22 = sw[(2*DM+cglob)*3+2];
  float sb0 = sb[cglob], sb1 = sb[DM+cglob], sb2 = sb[2*DM+cglob];
  size_t ob = ((size_t)(b * DM + cglob)) * L_SEQ + t0;
  for (int q = 0; q < 16; ++q){
    int tt = rr * 16 + q;
    float x0v = w00*s[0][cc][tt] + w01*s[0][cc][tt+1] + w02*s[0][cc][tt+2] + sb0;
    float x1v = w10*s[1][cc][tt] + w11*s[1][cc][tt+1] + w12*s[1][cc][tt+2] + sb1;
    float vv  = w20*s[2][cc][tt] + w21*s[2][cc][tt+1] + w22*s[2][cc][tt+2] + sb2;
    x0Out[ob + tt] = f2bf(x0v);
    gOut[ob + tt]  = f2bf(vv * x1v);
  }
}

// ---------------- FFT conv: 3-phase radix-16 register FFT, 2 channels packed ----
// fwd: n = n1+16*n2+256*n3 -> k = k3+16*k2+256*k1; thread t = n1+16*hi
__global__ __launch_bounds__(256) void k_fftconv(const u16* __restrict__ g, const u16* __restrict__ x0,
                          const float2* __restrict__ Kf, const float* __restrict__ fbias,
                          u16* __restrict__ z){
  int c0 = blockIdx.x * 2;
  int b = blockIdx.y;
  int t = threadIdx.x;
  __shared__ float2 S[4352];
  const size_t row0 = ((size_t)(b * DM + c0)) * L_SEQ;
  const size_t row1 = row0 + L_SEQ;
  const int n1 = t & 15, hi = t >> 4;
  float2 r[16];
  // ---- fwd stage 1: FFT16 over n3 (global stride 256); upper half zero
  #pragma unroll
  for (int n3 = 0; n3 < 8; ++n3){
    int n = t + (n3 << 8);
    r[n3] = make_float2(bf2f(g[row0 + n]), bf2f(g[row1 + n]));
    r[n3 + 8] = make_float2(0.f, 0.f);
  }
  fft16<1>(r);
  // twiddle W_256^{n2*k3} (n2=hi); write L1[k3][n2][n1]
  #pragma unroll
  for (int k3 = 0; k3 < 16; ++k3){
    float sn, cs; sincos_rev(-(float)(hi * k3) * (1.0f/256.0f), sn, cs);
    S[P16(k3*256 + hi*16 + n1)] = cmulf(r[BR4[k3]], cs, sn);
  }
  __syncthreads();
  // ---- fwd stage 2: thread (n1, k3=hi): gather over n2
  #pragma unroll
  for (int n2 = 0; n2 < 16; ++n2)
    r[n2] = S[P16(hi*256 + n2*16 + n1)];
  __syncthreads();
  fft16<1>(r);
  // twiddle W_4096^{n1*(k3+16*k2)}; write L2[k2][k3][n1] (k3=hi)
  #pragma unroll
  for (int k2 = 0; k2 < 16; ++k2){
    float sn, cs; sincos_rev(-(float)(n1 * (hi + 16*k2)) * (1.0f/4096.0f), sn, cs);
    S[P16(k2*256 + hi*16 + n1)] = cmulf(r[BR4[k2]], cs, sn);
  }
  __syncthreads();
  // ---- fwd stage 3: thread (k3=n1, k2=hi): gather over old-n1
  #pragma unroll
  for (int m = 0; m < 16; ++m)
    r[m] = S[P16(hi*256 + n1*16 + m)];
  __syncthreads();
  fft16<1>(r);
  // Z[k1]=r[BR4[k1]] at bin t+256*k1; publish to S (flat idx)
  #pragma unroll
  for (int k1 = 0; k1 < 16; ++k1)
    S[P16(t + (k1 << 8))] = r[BR4[k1]];
  __syncthreads();
  // ---- pointwise: unpack 2 real spectra with conj partner, mul, repack
  const float2* kf0 = Kf + (size_t)c0 * NFFT;
  const float2* kf1 = kf0 + NFFT;
  int mt = (256 - t) & 255;
  float2 y[16];
  #pragma unroll
  for (int k1 = 0; k1 < 16; ++k1){
    int k = t + (k1 << 8);
    int mk1 = (t == 0) ? ((16 - k1) & 15) : (15 - k1);
    float2 Zk = r[BR4[k1]];
    float2 Zm = S[P16(mt + (mk1 << 8))];
    float2 K0 = kf0[k], K1 = kf1[k];
    float gar = 0.5f*(Zk.x + Zm.x), gai = 0.5f*(Zk.y - Zm.y);
    float gbr = 0.5f*(Zk.y + Zm.y), gbi = 0.5f*(Zm.x - Zk.x);
    float yar = gar*K0.x - gai*K0.y, yai = gar*K0.y + gai*K0.x;
    float ybr = gbr*K1.x - gbi*K1.y, ybi = gbr*K1.y + gbi*K1.x;
    y[k1] = make_float2(yar - ybi, yai + ybr);
  }
  // ---- inverse stage A: FFT16+ over k1 (already in registers)
  fft16<-1>(y);
  __syncthreads();  // all partner reads done before overwriting S
  // twiddle W+_256^{m2*n3} (m2=hi); write L1[n3][m2][m1=n1]
  #pragma unroll
  for (int n3 = 0; n3 < 16; ++n3){
    float sn, cs; sincos_rev((float)(hi * n3) * (1.0f/256.0f), sn, cs);
    S[P16(n3*256 + hi*16 + n1)] = cmulf(y[BR4[n3]], cs, sn);
  }
  __syncthreads();
  // ---- inverse stage B: thread (m1=n1, n3=hi): gather over m2
  #pragma unroll
  for (int m2 = 0; m2 < 16; ++m2)
    r[m2] = S[P16(hi*256 + m2*16 + n1)];
  __syncthreads();
  fft16<-1>(r);
  // twiddle W+_4096^{m1*(n3+16*n2)}; write L2[n2][n3][m1] (n3=hi)
  #pragma unroll
  for (int nn2 = 0; nn2 < 16; ++nn2){
    float sn, cs; sincos_rev((float)(n1 * (hi + 16*nn2)) * (1.0f/4096.0f), sn, cs);
    S[P16(nn2*256 + hi*16 + n1)] = cmulf(r[BR4[nn2]], cs, sn);
  }
  __syncthreads();
  // ---- inverse stage C: thread (n3=n1, n2=hi): gather over m1
  #pragma unroll
  for (int m = 0; m < 16; ++m)
    r[m] = S[P16(hi*256 + n1*16 + m)];
  fft16<-1>(r);
  // y[n] at n = t+256*q is r[BR4[q]]; need q<8 only (n<2048)
  float fb0 = fbias[c0], fb1 = fbias[c0+1];
  #pragma unroll
  for (int q = 0; q < 8; ++q){
    int n = t + (q << 8);
    float2 val = r[BR4[q]];
    float g0 = bf2f(g[row0 + n]), g1 = bf2f(g[row1 + n]);
    float x00 = bf2f(x0[row0 + n]), x01 = bf2f(x0[row1 + n]);
    z[row0 + n] = f2bf((val.x + g0*fb0) * x00);
    z[row1 + n] = f2bf((val.y + g1*fb1) * x01);
  }
}

// ---------------- transpose z: (b,d,l) bf16 -> (b,l,d) bf16 ----------------
__global__ void k_transpose_z(const u16* __restrict__ zin, u16* __restrict__ zout){
  __shared__ u16 tile[32][33];
  int l0 = blockIdx.x * 32, d0 = blockIdx.y * 32, b = blockIdx.z;
  int x = threadIdx.x, y = threadIdx.y;
  for (int i = 0; i < 4; ++i){
    int d = d0 + y + i*8;
    tile[y + i*8][x] = zin[((size_t)(b * DM + d)) * L_SEQ + l0 + x];
  }
  __syncthreads();
  for (int i = 0; i < 4; ++i){
    int l = l0 + y + i*8;
    zout[((size_t)(b * L_SEQ + l)) * DM + d0 + x] = tile[x][y + i*8];
  }
}

extern "C" void kernel_launch(void* const* d_in, const int* in_sizes, int n_in,
                              void* d_out, int out_size, void* d_ws, size_t ws_size,
                              hipStream_t stream){
  (void)in_sizes; (void)n_in; (void)out_size; (void)ws_size;
  const float* u       = (const float*)d_in[0];
  const float* in_w    = (const float*)d_in[1];
  const float* in_b    = (const float*)d_in[2];
  const float* short_w = (const float*)d_in[3];
  const float* short_b = (const float*)d_in[4];
  const float* w0 = (const float*)d_in[5];
  const float* b0 = (const float*)d_in[6];
  const float* f0 = (const float*)d_in[7];
  const float* w1 = (const float*)d_in[8];
  const float* b1 = (const float*)d_in[9];
  const float* f1 = (const float*)d_in[10];
  const float* w2 = (const float*)d_in[11];
  const float* b2 = (const float*)d_in[12];
  const float* f2 = (const float*)d_in[13];
  const float* w3 = (const float*)d_in[14];
  const float* fbias = (const float*)d_in[15];
  const float* out_w = (const float*)d_in[16];
  const float* out_b = (const float*)d_in[17];
  float* out = (float*)d_out;

  char* ws = (char*)d_ws;
  size_t off = 0;
  auto alloc = [&](size_t bytes)->void*{
    void* p = ws + off; off += (bytes + 255) & ~(size_t)255; return p;
  };
  const int M = BATCH * L_SEQ; // 8192
  u16*   u_bf  = (u16*)  alloc((size_t)M * DM * 2);       // later reused as z
  u16*   inwT  = (u16*)  alloc((size_t)TW * DM * 2);
  u16*   outwT = (u16*)  alloc((size_t)DM * DM * 2);
  float* H2    = (float*)alloc((size_t)L_SEQ * 64 * 4);
  float2* Kf   = (float2*)alloc((size_t)DM * NFFT * 8);
  u16*   up    = (u16*)  alloc((size_t)M * TW * 2);       // later reused as zT
  u16*   gbuf  = (u16*)  alloc((size_t)BATCH * DM * L_SEQ * 2);
  u16*   x0buf = (u16*)  alloc((size_t)BATCH * DM * L_SEQ * 2);
  u16*   z  = u_bf;   // alias: u_bf dead after gemm1
  u16*   zT = up;     // alias: up dead after shortconv

  k_convert_u<<<2048, 256, 0, stream>>>((const float4*)u, u_bf, (M * DM) / 4);
  k_transpose_w<<<dim3(TW/32, DM/32), dim3(32, 8), 0, stream>>>(in_w, inwT, DM, TW);
  k_transpose_w<<<dim3(DM/32, DM/32), dim3(32, 8), 0, stream>>>(out_w, outwT, DM, DM);
  k_filter_h2<<<L_SEQ, 64, 0, stream>>>(w0, b0, f0, w1, b1, f1, w2, b2, f2, H2);
  k_filter_fft<<<DM/2, 256, 0, stream>>>(H2, w3, Kf);
  k_gemm<true><<<dim3(TW/128, M/128), 256, 0, stream>>>(u_bf, inwT, in_b, up, M, TW, DM);
  k_shortconv<<<dim3(L_SEQ/128, DM/32, BATCH), 256, 0, stream>>>(up, short_w, short_b, gbuf, x0buf);
  k_fftconv<<<dim3(DM/2, BATCH), 256, 0, stream>>>(gbuf, x0buf, Kf, fbias, z);
  k_transpose_z<<<dim3(L_SEQ/32, DM/32, BATCH), dim3(32, 8), 0, stream>>>(z, zT);
  k_gemm<false><<<dim3(DM/128, M/128), 256, 0, stream>>>(zT, outwT, out_b, out, M, DM, DM);
}

// Round 4
// 281.235 us; speedup vs baseline: 1.5428x; 1.0088x over previous
//
#include <hip/hip_runtime.h>
#include <stdint.h>

typedef unsigned short u16;
typedef __attribute__((ext_vector_type(8))) short short8;
typedef __attribute__((ext_vector_type(4))) float f32x4;

#define PI_F 3.14159265358979323846f
#define L_SEQ 2048
#define NFFT 4096
#define DM 1024
#define TW 3072
#define BATCH 4

__device__ __forceinline__ u16 f2bf(float f){
  union { float f; uint32_t u; } v; v.f = f;
  uint32_t r = v.u + 0x7fffu + ((v.u >> 16) & 1u);
  return (u16)(r >> 16);
}
__device__ __forceinline__ float bf2f(u16 h){
  union { uint32_t u; float f; } v; v.u = ((uint32_t)h) << 16;
  return v.f;
}

__device__ __forceinline__ void async16(const void* g, void* l){
  __builtin_amdgcn_global_load_lds(
      (const __attribute__((address_space(1))) void*)g,
      (__attribute__((address_space(3))) void*)l, 16, 0, 0);
}

// hardware sin/cos, input in REVOLUTIONS (angle = 2*pi*rev)
__device__ __forceinline__ void sincos_rev(float rev, float& sn, float& cs){
  asm("v_sin_f32 %0, %1" : "=v"(sn) : "v"(rev));
  asm("v_cos_f32 %0, %1" : "=v"(cs) : "v"(rev));
}

__device__ __forceinline__ float2 cmulf(float2 a, float c, float s){
  return make_float2(a.x*c - a.y*s, a.x*s + a.y*c);
}

__device__ __forceinline__ int Pold(int i){ return i + (i >> 5); }
__device__ __forceinline__ int P16(int i){ return i + (i >> 4); }
__device__ __forceinline__ int brv12(int k){ return (int)(__brev((unsigned)k) >> 20); }

__device__ static constexpr int BR4[16] = {0,8,4,12,2,10,6,14,1,9,5,13,3,11,7,15};

template<int SGN>
__device__ __forceinline__ void fft16(float2* a){
  const float s = (float)SGN;
  static constexpr float tc[8]  = {1.f, 0.92387953f, 0.70710678f, 0.38268343f,
                                   0.f, -0.38268343f, -0.70710678f, -0.92387953f};
  static constexpr float ts_[8] = {0.f, -0.38268343f, -0.70710678f, -0.92387953f,
                                   -1.f, -0.92387953f, -0.70710678f, -0.38268343f};
  #pragma unroll
  for (int j = 0; j < 8; ++j){
    float2 u = a[j], v = a[j+8];
    float2 d = make_float2(u.x - v.x, u.y - v.y);
    a[j] = make_float2(u.x + v.x, u.y + v.y);
    a[j+8] = cmulf(d, tc[j], s*ts_[j]);
  }
  #pragma unroll
  for (int g = 0; g < 2; ++g){
    int b = g*8;
    #pragma unroll
    for (int j = 0; j < 4; ++j){
      float2 u = a[b+j], v = a[b+j+4];
      float2 d = make_float2(u.x - v.x, u.y - v.y);
      a[b+j] = make_float2(u.x + v.x, u.y + v.y);
      a[b+j+4] = cmulf(d, tc[2*j], s*ts_[2*j]);
    }
  }
  #pragma unroll
  for (int g = 0; g < 4; ++g){
    int b = g*4;
    #pragma unroll
    for (int j = 0; j < 2; ++j){
      float2 u = a[b+j], v = a[b+j+2];
      float2 d = make_float2(u.x - v.x, u.y - v.y);
      a[b+j] = make_float2(u.x + v.x, u.y + v.y);
      a[b+j+2] = (j == 0) ? d : cmulf(d, 0.f, -s);
    }
  }
  #pragma unroll
  for (int g = 0; g < 8; ++g){
    int b = g*2;
    float2 u = a[b], v = a[b+1];
    a[b] = make_float2(u.x + v.x, u.y + v.y);
    a[b+1] = make_float2(u.x - v.x, u.y - v.y);
  }
}

// ---------------- convert u (fp32 -> bf16), vectorized ----------------
__global__ void k_convert_u(const float4* __restrict__ in, u16* __restrict__ outp, int n4){
  int idx = blockIdx.x * blockDim.x + threadIdx.x;
  int stride = gridDim.x * blockDim.x;
  for (int i = idx; i < n4; i += stride){
    float4 v = in[i];
    u16 r0 = f2bf(v.x), r1 = f2bf(v.y), r2 = f2bf(v.z), r3 = f2bf(v.w);
    u16* o = outp + (size_t)i * 4;
    o[0] = r0; o[1] = r1; o[2] = r2; o[3] = r3;
  }
}

// ---------------- transpose weight fp32 (K,N) -> bf16 (N,K) ----------------
__global__ void k_transpose_w(const float* __restrict__ in, u16* __restrict__ outp, int K, int N){
  __shared__ float tile[32][33];
  int n0 = blockIdx.x * 32, k0 = blockIdx.y * 32;
  int x = threadIdx.x, y = threadIdx.y;
  for (int i = 0; i < 4; ++i)
    tile[y + i*8][x] = in[(size_t)(k0 + y + i*8) * N + n0 + x];
  __syncthreads();
  for (int i = 0; i < 4; ++i)
    outp[(size_t)(n0 + y + i*8) * K + k0 + x] = f2bf(tile[x][y + i*8]);
}

// ---------------- filter MLP: H2 (2048 x 64) ----------------
__global__ void k_filter_h2(const float* __restrict__ w0, const float* __restrict__ b0, const float* __restrict__ f0,
                            const float* __restrict__ w1, const float* __restrict__ b1, const float* __restrict__ f1,
                            const float* __restrict__ w2, const float* __restrict__ b2, const float* __restrict__ f2,
                            float* __restrict__ H2){
  int t = blockIdx.x;
  int j = threadIdx.x; // 0..63
  float tn = t * (1.0f / 2047.0f);
  float ph = 1e-4f * 2.0f * PI_F * (float)t * (1.0f / 2048.0f);
  float z0 = tn, z1 = cosf(ph), z2 = -sinf(ph);
  __shared__ float hs[64];
  float pre = z0 * w0[j] + z1 * w0[64 + j] + z2 * w0[128 + j] + b0[j];
  float h = sinf(f0[j] * pre);
  hs[j] = h;
  __syncthreads();
  float acc = b1[j];
  for (int i = 0; i < 64; ++i) acc += hs[i] * w1[i*64 + j];
  h = sinf(f1[j] * acc);
  __syncthreads();
  hs[j] = h;
  __syncthreads();
  acc = b2[j];
  for (int i = 0; i < 64; ++i) acc += hs[i] * w2[i*64 + j];
  h = sinf(f2[j] * acc);
  H2[t*64 + j] = h;
}

// ---------------- old-style forward stages (filter precompute only) ----------
__device__ __forceinline__ void fft_fwd_stages(float2* a, int tid){
  for (int p = 11; p >= 1; --p){
    int half = 1 << (p - 1);
    float nscale = -1.0f / (float)(1 << p);
    #pragma unroll 2
    for (int i = 0; i < 8; ++i){
      int bfi = tid + (i << 8);
      int j = bfi & (half - 1);
      int i0 = bfi + (bfi & ~(half - 1));
      int i1 = i0 + half;
      float2 u = a[Pold(i0)], v = a[Pold(i1)];
      float sn, cs; sincos_rev(nscale * (float)j, sn, cs);
      float dx = u.x - v.x, dy = u.y - v.y;
      a[Pold(i0)] = make_float2(u.x + v.x, u.y + v.y);
      a[Pold(i1)] = make_float2(dx*cs - dy*sn, dx*sn + dy*cs);
    }
    __syncthreads();
  }
}

// ---------------- filter spectra, 2 channels packed per FFT ----------------
__global__ void k_filter_fft(const float* __restrict__ H2, const float* __restrict__ w3,
                             float2* __restrict__ Kf){
  int c0 = blockIdx.x * 2, c1 = c0 + 1;
  int tid = threadIdx.x;
  __shared__ float2 a[4224];
  __shared__ float wcol[2][64];
  if (tid < 64){ wcol[0][tid] = w3[tid * DM + c0]; wcol[1][tid] = w3[tid * DM + c1]; }
  __syncthreads();
  float absd0 = 3.070113457325394f + 12.280453829301576f * ((float)c0 * (1.0f / 1023.0f));
  float absd1 = 3.070113457325394f + 12.280453829301576f * ((float)c1 * (1.0f / 1023.0f));
  for (int i = 0; i < 8; ++i){
    int t = tid + (i << 8);
    const float* hr = &H2[t * 64];
    float s0 = 0.f, s1 = 0.f;
    #pragma unroll 8
    for (int j = 0; j < 64; ++j){ float h = hr[j]; s0 += h * wcol[0][j]; s1 += h * wcol[1][j]; }
    float tn = (float)t * (1.0f / 2047.0f);
    float k0v = s0 * __expf(-tn * absd0);
    float k1v = s1 * __expf(-tn * absd1);
    float sn, cs; sincos_rev((float)t * (-1.0f / 4096.0f), sn, cs);
    a[Pold(t)] = make_float2(k0v, k1v);
    a[Pold(t + L_SEQ)] = make_float2(k0v*cs - k1v*sn, k0v*sn + k1v*cs);
  }
  __syncthreads();
  fft_fwd_stages(a, tid);
  const float inv = 1.0f / (float)NFFT;
  float2* kf0 = &Kf[(size_t)c0 * NFFT];
  float2* kf1 = kf0 + NFFT;
  for (int i = 0; i < 8; ++i){
    int k = tid + (i << 8);
    int m = (NFFT - k) & (NFFT - 1);
    float2 Zk = a[Pold(brv12(k))], Zm = a[Pold(brv12(m))];
    float gar = 0.5f*(Zk.x + Zm.x), gai = 0.5f*(Zk.y - Zm.y);
    float gbr = 0.5f*(Zk.y + Zm.y), gbi = 0.5f*(Zm.x - Zk.x);
    kf0[k] = make_float2(gar*inv, gai*inv);
    kf1[k] = make_float2(gbr*inv, gbi*inv);
    if (k > 0){
      kf0[NFFT - k] = make_float2(gar*inv, -gai*inv);
      kf1[NFFT - k] = make_float2(gbr*inv, -gbi*inv);
    } else {
      float2 Zn = a[Pold(1)];
      kf0[2048] = make_float2(Zn.x*inv, 0.f);
      kf1[2048] = make_float2(Zn.y*inv, 0.f);
    }
  }
}

// =================== 8-phase 256-tile GEMM (T1+T2+T3+T4+T5) ===================
// C(M,N) = A(M,K)bf16 * Bt(N,K)^T + bias.  512 threads, 2x4 waves.
// LDS per buffer: A kh-slabs [2][BM][32], B kh-slabs [2][BN][32], double-buffered.
// Swizzle: u16 col ^= ((row>>1)&3)<<3 (both on pre-swizzled global src and reads).
__device__ __forceinline__ void gbar(){ __builtin_amdgcn_s_barrier(); }
__device__ __forceinline__ void lgk0(){
  asm volatile("s_waitcnt lgkmcnt(0)" ::: "memory");
  __builtin_amdgcn_sched_barrier(0);
}
template<int V>
__device__ __forceinline__ void waitvm(){
  if constexpr (V == 8) asm volatile("s_waitcnt vmcnt(8)" ::: "memory");
  else if constexpr (V == 6) asm volatile("s_waitcnt vmcnt(6)" ::: "memory");
  else asm volatile("s_waitcnt vmcnt(0)" ::: "memory");
  __builtin_amdgcn_sched_barrier(0);
}

template<int BM, int BN, bool OUT_BF16>
__global__ __launch_bounds__(512, 2) void k_gemm8(const u16* __restrict__ A, const u16* __restrict__ Bt,
                                                  const float* __restrict__ bias, void* __restrict__ Cout,
                                                  int M, int N, int K){
  constexpr int MR  = BM / 32;   // M fragments per wave
  constexpr int NR  = BN / 64;   // N fragments per wave
  constexpr int MR2 = MR / 2;
  constexpr int LA  = BM / 128;  // loads/thread per A kh-slab
  constexpr int LB  = BN / 128;
  constexpr int V   = 2 * (LA + LB);
  __shared__ __align__(16) u16 lds[2 * 64 * (BM + BN)];
  const int tid = threadIdx.x;
  const int lane = tid & 63, w = tid >> 6;
  const int wm = w >> 2, wn = w & 3;
  const int lr = lane & 15, lk8 = (lane >> 4) * 8;
  const int NT = K >> 6;

  // XCD-aware swizzle (grid % 8 == 0), then m-fast decomposition
  const int NMT = M / BM;
  int nwg = gridDim.x;
  int swz = (blockIdx.x & 7) * (nwg >> 3) + (blockIdx.x >> 3);
  int m0 = (swz % NMT) * BM;
  int n0 = (swz / NMT) * BN;

  u16* baseA = lds;
  u16* baseB = lds + 2 * 64 * BM;

  auto stageA = [&](int kts, int db, int kh){
    int kc0 = (kts << 6) + kh * 32;
    u16* slab = baseA + db * (BM * 64) + kh * (BM * 32);
    #pragma unroll
    for (int q = 0; q < LA; ++q){
      int row = q * 128 + (tid >> 2);
      int cl = ((tid & 3) * 8) ^ (((row >> 1) & 3) << 3);
      async16(A + (size_t)(m0 + row) * K + kc0 + cl, slab + q * 4096 + (w << 9));
    }
  };
  auto stageB = [&](int kts, int db, int kh){
    int kc0 = (kts << 6) + kh * 32;
    u16* slab = baseB + db * (BN * 64) + kh * (BN * 32);
    #pragma unroll
    for (int q = 0; q < LB; ++q){
      int row = q * 128 + (tid >> 2);
      int cl = ((tid & 3) * 8) ^ (((row >> 1) & 3) << 3);
      async16(Bt + (size_t)(n0 + row) * K + kc0 + cl, slab + q * 4096 + (w << 9));
    }
  };

  f32x4 acc[MR][NR] = {};
  short8 af[MR2], bf[NR];

  auto readA = [&](int db, int kh, int mh){
    const u16* base = baseA + db * (BM * 64) + kh * (BM * 32);
    #pragma unroll
    for (int ii = 0; ii < MR2; ++ii){
      int ar = wm * (BM / 2) + (mh * MR2 + ii) * 16 + lr;
      af[ii] = *(const short8*)&base[ar * 32 + (lk8 ^ (((ar >> 1) & 3) << 3))];
    }
  };
  auto readB = [&](int db, int kh){
    const u16* base = baseB + db * (BN * 64) + kh * (BN * 32);
    #pragma unroll
    for (int j = 0; j < NR; ++j){
      int br = wn * (BN / 4) + j * 16 + lr;
      bf[j] = *(const short8*)&base[br * 32 + (lk8 ^ (((br >> 1) & 3) << 3))];
    }
  };

#define MFMA_HALF(mh)                                                          \
  __builtin_amdgcn_s_setprio(1);                                               \
  _Pragma("unroll")                                                            \
  for (int ii = 0; ii < MR2; ++ii)                                             \
    _Pragma("unroll")                                                          \
    for (int j = 0; j < NR; ++j)                                               \
      acc[(mh)*MR2 + ii][j] = __builtin_amdgcn_mfma_f32_16x16x32_bf16(         \
          af[ii], bf[j], acc[(mh)*MR2 + ii][j], 0, 0, 0);                      \
  __builtin_amdgcn_s_setprio(0);

  // prologue: 6 slab-units ahead
  stageA(0, 0, 0); stageB(0, 0, 0);
  stageA(0, 0, 1); stageB(0, 0, 1);
  stageA(1, 1, 0); stageB(1, 1, 0);
  waitvm<V>();
  gbar();

  for (int kt = 0; kt < NT; ++kt){
    int b = kt & 1, bn2 = b ^ 1;
    int t1 = (kt + 1 < NT) ? kt + 1 : 0;   // wrapped tail staging keeps vmcnt uniform
    int t2 = (kt + 2 < NT) ? kt + 2 : 0;
    // phase 0: kh0, mh0
    readB(b, 0); readA(b, 0, 0);
    stageA(t1, bn2, 1);
    gbar(); lgk0();
    MFMA_HALF(0)
    gbar();
    // phase 1: kh0, mh1
    readA(b, 0, 1);
    stageB(t1, bn2, 1);
    gbar(); lgk0();
    MFMA_HALF(1)
    waitvm<V>();
    gbar();
    // phase 2: kh1, mh0
    readB(b, 1); readA(b, 1, 0);
    stageA(t2, b, 0);
    gbar(); lgk0();
    MFMA_HALF(0)
    gbar();
    // phase 3: kh1, mh1
    readA(b, 1, 1);
    stageB(t2, b, 0);
    gbar(); lgk0();
    MFMA_HALF(1)
    waitvm<V>();
    gbar();
  }
#undef MFMA_HALF

  // epilogue: C/D layout col = lane&15, row = (lane>>4)*4 + r
  #pragma unroll
  for (int j = 0; j < NR; ++j){
    int col = n0 + wn * (BN / 4) + j * 16 + lr;
    float bv = bias[col];
    #pragma unroll
    for (int i = 0; i < MR; ++i){
      int rbase = m0 + wm * (BM / 2) + i * 16 + (lane >> 4) * 4;
      #pragma unroll
      for (int r = 0; r < 4; ++r){
        float val = acc[i][j][r] + bv;
        if (OUT_BF16) ((u16*)Cout)[(size_t)(rbase + r) * N + col] = f2bf(val);
        else ((float*)Cout)[(size_t)(rbase + r) * N + col] = val;
      }
    }
  }
}

// ---------------- short conv + gate + transpose to (b,d,l) ----------------
__global__ void k_shortconv(const u16* __restrict__ up, const float* __restrict__ sw,
                            const float* __restrict__ sb,
                            u16* __restrict__ gOut, u16* __restrict__ x0Out){
  __shared__ float s[3][32][130];
  int t0 = blockIdx.x * 128;
  int c0 = blockIdx.y * 32;
  int b  = blockIdx.z;
  int tid = threadIdx.x;
  int cc = tid & 31, rr = tid >> 5;
  for (int g2 = 0; g2 < 3; ++g2){
    for (int r = rr; r < 130; r += 8){
      int t = t0 + r - 2;
      float v = 0.f;
      if (t >= 0) v = bf2f(up[((size_t)(b * L_SEQ + t)) * TW + g2 * DM + c0 + cc]);
      s[g2][cc][r] = v;
    }
  }
  __syncthreads();
  int cglob = c0 + cc;
  float w00 = sw[cglob*3+0],        w01 = sw[cglob*3+1],        w02 = sw[cglob*3+2];
  float w10 = sw[(DM+cglob)*3+0],   w11 = sw[(DM+cglob)*3+1],   w12 = sw[(DM+cglob)*3+2];
  float w20 = sw[(2*DM+cglob)*3+0], w21 = sw[(2*DM+cglob)*3+1], w22 = sw[(2*DM+cglob)*3+2];
  float sb0 = sb[cglob], sb1 = sb[DM+cglob], sb2 = sb[2*DM+cglob];
  size_t ob = ((size_t)(b * DM + cglob)) * L_SEQ + t0;
  for (int q = 0; q < 16; ++q){
    int tt = rr * 16 + q;
    float x0v = w00*s[0][cc][tt] + w01*s[0][cc][tt+1] + w02*s[0][cc][tt+2] + sb0;
    float x1v = w10*s[1][cc][tt] + w11*s[1][cc][tt+1] + w12*s[1][cc][tt+2] + sb1;
    float vv  = w20*s[2][cc][tt] + w21*s[2][cc][tt+1] + w22*s[2][cc][tt+2] + sb2;
    x0Out[ob + tt] = f2bf(x0v);
    gOut[ob + tt]  = f2bf(vv * x1v);
  }
}

// ---------------- FFT conv: 3-phase radix-16 register FFT, 2 channels packed ----
__global__ __launch_bounds__(256) void k_fftconv(const u16* __restrict__ g, const u16* __restrict__ x0,
                          const float2* __restrict__ Kf, const float* __restrict__ fbias,
                          u16* __restrict__ z){
  int c0 = blockIdx.x * 2;
  int b = blockIdx.y;
  int t = threadIdx.x;
  __shared__ float2 S[4352];
  const size_t row0 = ((size_t)(b * DM + c0)) * L_SEQ;
  const size_t row1 = row0 + L_SEQ;
  const int n1 = t & 15, hi = t >> 4;
  float2 r[16];
  #pragma unroll
  for (int n3 = 0; n3 < 8; ++n3){
    int n = t + (n3 << 8);
    r[n3] = make_float2(bf2f(g[row0 + n]), bf2f(g[row1 + n]));
    r[n3 + 8] = make_float2(0.f, 0.f);
  }
  fft16<1>(r);
  #pragma unroll
  for (int k3 = 0; k3 < 16; ++k3){
    float sn, cs; sincos_rev(-(float)(hi * k3) * (1.0f/256.0f), sn, cs);
    S[P16(k3*256 + hi*16 + n1)] = cmulf(r[BR4[k3]], cs, sn);
  }
  __syncthreads();
  #pragma unroll
  for (int n2 = 0; n2 < 16; ++n2)
    r[n2] = S[P16(hi*256 + n2*16 + n1)];
  __syncthreads();
  fft16<1>(r);
  #pragma unroll
  for (int k2 = 0; k2 < 16; ++k2){
    float sn, cs; sincos_rev(-(float)(n1 * (hi + 16*k2)) * (1.0f/4096.0f), sn, cs);
    S[P16(k2*256 + hi*16 + n1)] = cmulf(r[BR4[k2]], cs, sn);
  }
  __syncthreads();
  #pragma unroll
  for (int m = 0; m < 16; ++m)
    r[m] = S[P16(hi*256 + n1*16 + m)];
  __syncthreads();
  fft16<1>(r);
  #pragma unroll
  for (int k1 = 0; k1 < 16; ++k1)
    S[P16(t + (k1 << 8))] = r[BR4[k1]];
  __syncthreads();
  const float2* kf0 = Kf + (size_t)c0 * NFFT;
  const float2* kf1 = kf0 + NFFT;
  int mt = (256 - t) & 255;
  float2 y[16];
  #pragma unroll
  for (int k1 = 0; k1 < 16; ++k1){
    int k = t + (k1 << 8);
    int mk1 = (t == 0) ? ((16 - k1) & 15) : (15 - k1);
    float2 Zk = r[BR4[k1]];
    float2 Zm = S[P16(mt + (mk1 << 8))];
    float2 K0 = kf0[k], K1 = kf1[k];
    float gar = 0.5f*(Zk.x + Zm.x), gai = 0.5f*(Zk.y - Zm.y);
    float gbr = 0.5f*(Zk.y + Zm.y), gbi = 0.5f*(Zm.x - Zk.x);
    float yar = gar*K0.x - gai*K0.y, yai = gar*K0.y + gai*K0.x;
    float ybr = gbr*K1.x - gbi*K1.y, ybi = gbr*K1.y + gbi*K1.x;
    y[k1] = make_float2(yar - ybi, yai + ybr);
  }
  fft16<-1>(y);
  __syncthreads();
  #pragma unroll
  for (int n3 = 0; n3 < 16; ++n3){
    float sn, cs; sincos_rev((float)(hi * n3) * (1.0f/256.0f), sn, cs);
    S[P16(n3*256 + hi*16 + n1)] = cmulf(y[BR4[n3]], cs, sn);
  }
  __syncthreads();
  #pragma unroll
  for (int m2 = 0; m2 < 16; ++m2)
    r[m2] = S[P16(hi*256 + m2*16 + n1)];
  __syncthreads();
  fft16<-1>(r);
  #pragma unroll
  for (int nn2 = 0; nn2 < 16; ++nn2){
    float sn, cs; sincos_rev((float)(n1 * (hi + 16*nn2)) * (1.0f/4096.0f), sn, cs);
    S[P16(nn2*256 + hi*16 + n1)] = cmulf(r[BR4[nn2]], cs, sn);
  }
  __syncthreads();
  #pragma unroll
  for (int m = 0; m < 16; ++m)
    r[m] = S[P16(hi*256 + n1*16 + m)];
  fft16<-1>(r);
  float fb0 = fbias[c0], fb1 = fbias[c0+1];
  #pragma unroll
  for (int q = 0; q < 8; ++q){
    int n = t + (q << 8);
    float2 val = r[BR4[q]];
    float g0 = bf2f(g[row0 + n]), g1 = bf2f(g[row1 + n]);
    float x00 = bf2f(x0[row0 + n]), x01 = bf2f(x0[row1 + n]);
    z[row0 + n] = f2bf((val.x + g0*fb0) * x00);
    z[row1 + n] = f2bf((val.y + g1*fb1) * x01);
  }
}

// ---------------- transpose z: (b,d,l) bf16 -> (b,l,d) bf16 ----------------
__global__ void k_transpose_z(const u16* __restrict__ zin, u16* __restrict__ zout){
  __shared__ u16 tile[32][33];
  int l0 = blockIdx.x * 32, d0 = blockIdx.y * 32, b = blockIdx.z;
  int x = threadIdx.x, y = threadIdx.y;
  for (int i = 0; i < 4; ++i){
    int d = d0 + y + i*8;
    tile[y + i*8][x] = zin[((size_t)(b * DM + d)) * L_SEQ + l0 + x];
  }
  __syncthreads();
  for (int i = 0; i < 4; ++i){
    int l = l0 + y + i*8;
    zout[((size_t)(b * L_SEQ + l)) * DM + d0 + x] = tile[x][y + i*8];
  }
}

extern "C" void kernel_launch(void* const* d_in, const int* in_sizes, int n_in,
                              void* d_out, int out_size, void* d_ws, size_t ws_size,
                              hipStream_t stream){
  (void)in_sizes; (void)n_in; (void)out_size; (void)ws_size;
  const float* u       = (const float*)d_in[0];
  const float* in_w    = (const float*)d_in[1];
  const float* in_b    = (const float*)d_in[2];
  const float* short_w = (const float*)d_in[3];
  const float* short_b = (const float*)d_in[4];
  const float* w0 = (const float*)d_in[5];
  const float* b0 = (const float*)d_in[6];
  const float* f0 = (const float*)d_in[7];
  const float* w1 = (const float*)d_in[8];
  const float* b1 = (const float*)d_in[9];
  const float* f1 = (const float*)d_in[10];
  const float* w2 = (const float*)d_in[11];
  const float* b2 = (const float*)d_in[12];
  const float* f2 = (const float*)d_in[13];
  const float* w3 = (const float*)d_in[14];
  const float* fbias = (const float*)d_in[15];
  const float* out_w = (const float*)d_in[16];
  const float* out_b = (const float*)d_in[17];
  float* out = (float*)d_out;

  char* ws = (char*)d_ws;
  size_t off = 0;
  auto alloc = [&](size_t bytes)->void*{
    void* p = ws + off; off += (bytes + 255) & ~(size_t)255; return p;
  };
  const int M = BATCH * L_SEQ; // 8192
  u16*   u_bf  = (u16*)  alloc((size_t)M * DM * 2);       // later reused as z
  u16*   inwT  = (u16*)  alloc((size_t)TW * DM * 2);
  u16*   outwT = (u16*)  alloc((size_t)DM * DM * 2);
  float* H2    = (float*)alloc((size_t)L_SEQ * 64 * 4);
  float2* Kf   = (float2*)alloc((size_t)DM * NFFT * 8);
  u16*   up    = (u16*)  alloc((size_t)M * TW * 2);       // later reused as zT
  u16*   gbuf  = (u16*)  alloc((size_t)BATCH * DM * L_SEQ * 2);
  u16*   x0buf = (u16*)  alloc((size_t)BATCH * DM * L_SEQ * 2);
  u16*   z  = u_bf;   // alias: u_bf dead after gemm1
  u16*   zT = up;     // alias: up dead after shortconv

  k_convert_u<<<2048, 256, 0, stream>>>((const float4*)u, u_bf, (M * DM) / 4);
  k_transpose_w<<<dim3(TW/32, DM/32), dim3(32, 8), 0, stream>>>(in_w, inwT, DM, TW);
  k_transpose_w<<<dim3(DM/32, DM/32), dim3(32, 8), 0, stream>>>(out_w, outwT, DM, DM);
  k_filter_h2<<<L_SEQ, 64, 0, stream>>>(w0, b0, f0, w1, b1, f1, w2, b2, f2, H2);
  k_filter_fft<<<DM/2, 256, 0, stream>>>(H2, w3, Kf);
  k_gemm8<256, 256, true><<<dim3((M/256)*(TW/256)), 512, 0, stream>>>(u_bf, inwT, in_b, up, M, TW, DM);
  k_shortconv<<<dim3(L_SEQ/128, DM/32, BATCH), 256, 0, stream>>>(up, short_w, short_b, gbuf, x0buf);
  k_fftconv<<<dim3(DM/2, BATCH), 256, 0, stream>>>(gbuf, x0buf, Kf, fbias, z);
  k_transpose_z<<<dim3(L_SEQ/32, DM/32, BATCH), dim3(32, 8), 0, stream>>>(z, zT);
  k_gemm8<256, 128, false><<<dim3((M/256)*(DM/128)), 512, 0, stream>>>(zT, outwT, out_b, out, M, DM, DM);
}